// Round 9
// baseline (4275.126 us; speedup 1.0000x reference)
//
#include <hip/hip_runtime.h>
#include <stdint.h>

// CipherRNN: B=64, S=1024, V=128, E=512, H=512, L=2, O=256
#define B_ 64
#define S_ 1024
#define V_ 128
#define E_ 512
#define H_ 512
#define O_ 256
#define PSLOT (B_ * H_ * 2)     // 65536 u32 per ring slot of {data,tag} pairs

typedef __attribute__((ext_vector_type(8))) short bf16x8;
typedef __attribute__((ext_vector_type(4))) float f32x4;
typedef __attribute__((ext_vector_type(4))) unsigned int u32x4;
typedef __attribute__((ext_vector_type(2))) unsigned int u32x2;
typedef unsigned short u16;
typedef unsigned int u32;

__device__ __forceinline__ u16 f2bf(float f) {
  unsigned u = __builtin_bit_cast(unsigned, f);
  u = u + 0x7FFFu + ((u >> 16) & 1u);   // RNE
  return (u16)(u >> 16);
}
__device__ __forceinline__ float bf2f(u16 h) {
  unsigned u = ((unsigned)h) << 16;
  return __builtin_bit_cast(float, u);
}
// fast tanh via exp2 (~1e-7 rel err; numerically proven rounds 4/7/8)
__device__ __forceinline__ float fast_tanh(float x) {
  float a = __builtin_amdgcn_exp2f(x * 2.8853900817779268f);
  return 1.0f - 2.0f * __builtin_amdgcn_rcpf(a + 1.0f);
}
__device__ __forceinline__ u32 pk_hi(u32 a, u32 b) { return (a & 0xffffu) | (b << 16); }
__device__ __forceinline__ u32 pk_lo(u32 a, u32 b) { return (a >> 16) | (b & 0xffff0000u); }

// ---- L3-coherent (bypass L1+L2, zero cache-maintenance) ops — proven r3..r8
__device__ __forceinline__ u32x4 ld_sc1_x4(const u32* p) {
  u32x4 v;
  asm volatile("global_load_dwordx4 %0, %1, off sc0 sc1" : "=v"(v) : "v"(p));
  return v;
}
__device__ __forceinline__ u32x2 ld_sc1_x2(const u32* p) {
  u32x2 v;
  asm volatile("global_load_dwordx2 %0, %1, off sc0 sc1" : "=v"(v) : "v"(p));
  return v;
}
__device__ __forceinline__ void st_sc1_x2(u32* p, u32 d, u32 tag) {
  u32x2 v = {d, tag};   // 8B aligned single store: pair single-copy atomic (r4/r8 proven)
  asm volatile("global_store_dwordx2 %0, %1, off sc0 sc1" :: "v"(p), "v"(v) : "memory");
}
__device__ __forceinline__ void st_sc1_u32(u32* p, u32 v) {
  asm volatile("global_store_dword %0, %1, off sc0 sc1" :: "v"(p), "v"(v) : "memory");
}
__device__ __forceinline__ void st_short_nt(u16* p, u32 v) {
  asm volatile("global_store_short %0, %1, off nt" :: "v"(p), "v"(v) : "memory");
}
__device__ __forceinline__ void vm0_fence() {
  asm volatile("s_waitcnt vmcnt(0)" ::: "memory");
  __builtin_amdgcn_sched_barrier(0);
}
// tid0 flag-line poll (16B) — the only spin with nontrivial expected iterations
__device__ __forceinline__ void poll4(const u32* p, u32 tgt) {
  for (;;) {
    u32x4 v;
    asm volatile("global_load_dwordx4 %0, %1, off sc0 sc1\n\ts_waitcnt vmcnt(0)"
                 : "=v"(v) : "v"(p) : "memory");
    if (v.x >= tgt && v.y >= tgt && v.z >= tgt && v.w >= tgt) return;
    __builtin_amdgcn_s_sleep(1);
  }
}

// ---------------------------------------------------------------------------
// EW0[v][n] = sum_e emb[v][e]*Wxh0[n][e] + bh0[n]   (f32 exact, V=128)
// ---------------------------------------------------------------------------
__global__ void k_embed(const float* __restrict__ emb, const float* __restrict__ Wxh0,
                        const float* __restrict__ bh0, float* __restrict__ EW0) {
  __shared__ float es[E_];
  const int v = blockIdx.x;
  for (int e = threadIdx.x; e < E_; e += blockDim.x) es[e] = emb[v * E_ + e];
  __syncthreads();
  for (int h = threadIdx.x; h < H_; h += blockDim.x) {
    const float* wr = Wxh0 + (size_t)h * E_;
    float acc = bh0[h];
    #pragma unroll 4
    for (int e = 0; e < E_; e += 4)
      acc += es[e] * wr[e] + es[e+1] * wr[e+1] + es[e+2] * wr[e+2] + es[e+3] * wr[e+3];
    EW0[(size_t)v * H_ + h] = acc;
  }
}

// ---------------------------------------------------------------------------
// Persistent 3-stage pipeline. HYBRID sync: tagged {data,tag} pairs carry
// correctness (no producer drain before flag); tid0-only 16B hint-flag gates
// the block-wide one-shot tag-verified stage (no block-wide spinning).
// 48 blocks = 3 roles x 4 groups (16 batch rows) x 4 col-blocks (128 cols).
// ---------------------------------------------------------------------------
__global__ __launch_bounds__(512, 2) void k_pipe(
    const float* __restrict__ Whh, const float* __restrict__ Wxh,
    const int* __restrict__ ids, const float* __restrict__ EW0,
    const float* __restrict__ bh,
    u32* __restrict__ h0r,        // [16][64*512] pairs {packed hb|lb, tag}
    u32* __restrict__ x1r,        // [16][64*512] pairs {f32 bits, tag}
    u32* __restrict__ h1r,        // [4][64*512] pairs
    u16* __restrict__ h1full,     // [B*S][512] bf16
    u32* __restrict__ fa)         // flag arena (zeroed each call)
{
  __shared__ u32 lds_hi_w[2 * 4096];   // 2 bufs x 16 rows x 512 u16 cols (hi)
  __shared__ u32 lds_lo_w[2 * 4096];   // (lo)

  const int tid  = threadIdx.x;
  const int wave = tid >> 6, lane = tid & 63;
  const int l15 = lane & 15, lhi = lane >> 4;
  const int bid = blockIdx.x;
  const int role = bid >> 4, sub = bid & 15;
  const int g = sub >> 2, cb = sub & 3;
  const int n = cb * 128 + wave * 16 + l15;   // this lane's output column

  u32* h0f    = fa;            // [4g][16 slot][4 cb] hint flags
  u32* h1f    = fa + 256;      // [4g][16 slot][4 cb]
  u32* x1prog = fa + 512;      // [4g][4 cb] role1 progress (h0 ring backpressure)
  u32* r2prog = fa + 528;      // [4g][4 cb] role2 progress (x1 ring backpressure)

  // ---- resident weights (hi/lo bf16 B-fragments), plain cached loads ----
  const float* Wsel = (role == 0) ? Whh
                    : (role == 1) ? (Wxh + (size_t)H_ * H_)
                                  : (Whh + (size_t)H_ * H_);
  bf16x8 whi[16], wlo[16];
  {
    const float* wr = Wsel + (size_t)n * H_ + lhi * 8;
    #pragma unroll
    for (int ks = 0; ks < 16; ++ks) {
      const float* src = wr + ks * 32;
      bf16x8 h, l;
      #pragma unroll
      for (int j = 0; j < 8; ++j) {
        const float v = src[j];
        const u16 hb = f2bf(v);
        h[j] = (short)hb;
        l[j] = (short)f2bf(v - bf2f(hb));
      }
      whi[ks] = h; wlo[ks] = l;
    }
  }

  // A-frag swizzled LDS byte offsets: row=l15, granule = ks*4+lhi
  int aoff[16];
  {
    const int sw = l15 & 7;
    #pragma unroll
    for (int ks = 0; ks < 16; ++ks)
      aoff[ks] = l15 * 1024 + (((ks * 4 + lhi) ^ sw) << 4);
  }

  // staging geometry: 16 rows x 32 4-col chunks per 128-col slice
  const int sr = tid >> 5, sm = tid & 31;
  const int rowbase = (g * 16 + sr) * 512;     // pair-row base within a slot

  auto wr_lds = [&](int buf, int cs, u32 d0, u32 d1, u32 d2, u32 d3) {
    const int byte = buf * 16384 + sr * 1024 + (sm & 1) * 8 +
                     ((((cs << 4) + (sm >> 1)) ^ (sr & 7)) << 4);
    u32x2 hi = { pk_hi(d0, d1), pk_hi(d2, d3) };
    u32x2 lo = { pk_lo(d0, d1), pk_lo(d2, d3) };
    *(u32x2*)((char*)lds_hi_w + byte) = hi;
    *(u32x2*)((char*)lds_lo_w + byte) = lo;
  };

  // one-shot (expected) tag-verified stage of the 3 sibling 16x128 slices
  auto pollstage3 = [&](const u32* slot, u32 want, int buf) {
    const int c0 = (cb + 1) & 3, c1 = (cb + 2) & 3, c2 = (cb + 3) & 3;
    const u32* p0 = slot + ((rowbase + c0 * 128 + sm * 4) << 1);
    const u32* p1 = slot + ((rowbase + c1 * 128 + sm * 4) << 1);
    const u32* p2 = slot + ((rowbase + c2 * 128 + sm * 4) << 1);
    u32x4 a0, a1, b0, b1, d0, d1;
    for (;;) {
      a0 = ld_sc1_x4(p0); a1 = ld_sc1_x4(p0 + 4);
      b0 = ld_sc1_x4(p1); b1 = ld_sc1_x4(p1 + 4);
      d0 = ld_sc1_x4(p2); d1 = ld_sc1_x4(p2 + 4);
      vm0_fence();
      u32 bad = (a0.y ^ want) | (a0.w ^ want) | (a1.y ^ want) | (a1.w ^ want)
              | (b0.y ^ want) | (b0.w ^ want) | (b1.y ^ want) | (b1.w ^ want)
              | (d0.y ^ want) | (d0.w ^ want) | (d1.y ^ want) | (d1.w ^ want);
      if (!bad) break;
    }
    wr_lds(buf, c0, a0.x, a0.z, a1.x, a1.z);
    wr_lds(buf, c1, b0.x, b0.z, b1.x, b1.z);
    wr_lds(buf, c2, d0.x, d0.z, d1.x, d1.z);
  };

  // one-shot tag-verified stage of all 4 slices (role 1)
  auto pollstage4 = [&](const u32* slot, u32 want, int buf) {
    const u32* p0 = slot + ((rowbase + sm * 4) << 1);
    u32x4 q[8];
    for (;;) {
      #pragma unroll
      for (int c = 0; c < 4; ++c) {
        q[2*c]   = ld_sc1_x4(p0 + (c * 128 << 1));
        q[2*c+1] = ld_sc1_x4(p0 + (c * 128 << 1) + 4);
      }
      vm0_fence();
      u32 bad = 0;
      #pragma unroll
      for (int i = 0; i < 8; ++i) bad |= (q[i].y ^ want) | (q[i].w ^ want);
      if (!bad) break;
    }
    #pragma unroll
    for (int c = 0; c < 4; ++c)
      wr_lds(buf, c, q[2*c].x, q[2*c].z, q[2*c+1].x, q[2*c+1].z);
  };

  // emulated-fp32 matmul from LDS tile (3 independent MFMA chains)
  auto mm3 = [&](int buf, f32x4& out) {
    const char* bh_ = (const char*)lds_hi_w + buf * 16384;
    const char* bl_ = (const char*)lds_lo_w + buf * 16384;
    f32x4 c0 = {0.f,0.f,0.f,0.f}, c1 = c0, c2 = c0;
    #pragma unroll
    for (int ks = 0; ks < 16; ++ks) {
      bf16x8 ah = *(const bf16x8*)(bh_ + aoff[ks]);
      bf16x8 al = *(const bf16x8*)(bl_ + aoff[ks]);
      c0 = __builtin_amdgcn_mfma_f32_16x16x32_bf16(ah, whi[ks], c0, 0, 0, 0);
      c1 = __builtin_amdgcn_mfma_f32_16x16x32_bf16(al, whi[ks], c1, 0, 0, 0);
      c2 = __builtin_amdgcn_mfma_f32_16x16x32_bf16(ah, wlo[ks], c2, 0, 0, 0);
    }
    out = c0 + c1 + c2;
  };

  // epilogue self-write: own 4 outputs (col n, rows lhi*4+j) into LDS buf
  auto self_write = [&](int buf, const u16* hbv, const u16* lbv) {
    char* bh_ = (char*)lds_hi_w + buf * 16384;
    char* bl_ = (char*)lds_lo_w + buf * 16384;
    const int gcol = n >> 3, coff = (n & 7) * 2;
    #pragma unroll
    for (int j = 0; j < 4; ++j) {
      const int r = lhi * 4 + j;
      const int byte = r * 1024 + ((gcol ^ (r & 7)) << 4) + coff;
      *(u16*)(bh_ + byte) = hbv[j];
      *(u16*)(bl_ + byte) = lbv[j];
    }
  };

  if (role == 0) {                     // ======== layer-0 recurrence ========
    for (int t = 0; t < S_; ++t) {
      float ew[4];
      #pragma unroll
      for (int j = 0; j < 4; ++j) {
        const int b = g * 16 + lhi * 4 + j;
        ew[j] = EW0[(size_t)ids[b * S_ + t] * H_ + n];
      }
      const int cur = t & 1;
      f32x4 acc = {0.f,0.f,0.f,0.f};
      if (t > 0) mm3(cur, acc);        // buf cur holds h0[t-1]
      u32* wsl = h0r + (size_t)(t & 15) * PSLOT;
      u16 hbv[4], lbv[4];
      #pragma unroll
      for (int j = 0; j < 4; ++j) {
        const int b = g * 16 + lhi * 4 + j;
        const float h = fast_tanh(acc[j] + ew[j]);
        hbv[j] = f2bf(h);
        lbv[j] = f2bf(h - bf2f(hbv[j]));
        st_sc1_x2(wsl + (((size_t)b * 512 + n) << 1),
                  (u32)hbv[j] | ((u32)lbv[j] << 16), (u32)(t + 1));
      }
      self_write(cur ^ 1, hbv, lbv);
      __syncthreads();                 // all pair stores issued + LDS self done
      if (tid == 0) {
        st_sc1_u32(&h0f[((g << 4) | (t & 15)) * 4 + cb], (u32)(t + 1));  // hint, no drain
        if ((t & 7) == 0 && t >= 16) poll4(&x1prog[g * 4], (u32)(t - 8));
        if (t + 1 < S_) poll4(&h0f[((g << 4) | (t & 15)) * 4], (u32)(t + 1));
      }
      __syncthreads();
      if (t + 1 < S_) pollstage3(wsl, (u32)(t + 1), cur ^ 1);
      __syncthreads();
    }
  } else if (role == 1) {              // ======== x1 = h0 @ Wxh1^T + bh1 ========
    const float bias = bh[H_ + n];
    for (int t = 0; t < S_; ++t) {
      if (tid == 0) {
        poll4(&h0f[((g << 4) | (t & 15)) * 4], (u32)(t + 1));
        if ((t & 7) == 0 && t >= 16) poll4(&r2prog[g * 4], (u32)(t - 8));
      }
      __syncthreads();
      const int cur = t & 1;
      pollstage4(h0r + (size_t)(t & 15) * PSLOT, (u32)(t + 1), cur);
      __syncthreads();
      if (tid == 0 && (t & 7) == 7)    // h0[t] consumed -> release ring slots
        st_sc1_u32(&x1prog[g * 4 + cb], (u32)(t + 1));
      f32x4 acc;
      mm3(cur, acc);
      u32* xsl = x1r + (size_t)(t & 15) * PSLOT;
      #pragma unroll
      for (int j = 0; j < 4; ++j) {
        const int b = g * 16 + lhi * 4 + j;
        const float v = acc[j] + bias;
        st_sc1_x2(xsl + (((size_t)b * 512 + n) << 1),
                  __builtin_bit_cast(u32, v), (u32)(t + 1));   // no flag: role2 tag-polls
      }
    }
  } else {                             // ======== layer-1 recurrence ========
    u32 xvb[4];
    {                                   // pre-loop: tag-poll x1[0] (32B/thread)
      u32x2 xq[4];
      for (;;) {
        #pragma unroll
        for (int j = 0; j < 4; ++j) {
          const int b = g * 16 + lhi * 4 + j;
          xq[j] = ld_sc1_x2(x1r + (((size_t)b * 512 + n) << 1));
        }
        vm0_fence();
        u32 bad = 0;
        #pragma unroll
        for (int j = 0; j < 4; ++j) bad |= xq[j].y ^ 1u;
        if (!bad) break;
        __builtin_amdgcn_s_sleep(1);
      }
      #pragma unroll
      for (int j = 0; j < 4; ++j) xvb[j] = xq[j].x;
    }
    for (int t = 0; t < S_; ++t) {
      const int cur = t & 1;
      f32x4 acc = {0.f,0.f,0.f,0.f};
      if (t > 0) mm3(cur, acc);        // buf cur holds h1[t-1]
      u32* wsl = h1r + (size_t)(t & 3) * PSLOT;
      u16 hbv[4], lbv[4];
      #pragma unroll
      for (int j = 0; j < 4; ++j) {
        const int b = g * 16 + lhi * 4 + j;
        const float h = fast_tanh(acc[j] + __builtin_bit_cast(float, xvb[j]));
        hbv[j] = f2bf(h);
        lbv[j] = f2bf(h - bf2f(hbv[j]));
        st_sc1_x2(wsl + (((size_t)b * 512 + n) << 1),
                  (u32)hbv[j] | ((u32)lbv[j] << 16), (u32)(t + 1));
        st_short_nt(h1full + ((size_t)b * S_ + t) * H_ + n, (u32)hbv[j]);
      }
      self_write(cur ^ 1, hbv, lbv);
      __syncthreads();                 // all pair stores issued + LDS self done
      if (tid == 0) {
        st_sc1_u32(&h1f[((g << 4) | (t & 15)) * 4 + cb], (u32)(t + 1));  // hint
        if ((t & 7) == 7) st_sc1_u32(&r2prog[g * 4 + cb], (u32)(t + 1));
        if (t + 1 < S_) poll4(&h1f[((g << 4) | (t & 15)) * 4], (u32)(t + 1));
      }
      __syncthreads();
      if (t + 1 < S_) {
        pollstage3(wsl, (u32)(t + 1), cur ^ 1);
        // next-step x1 (own 32B, tag t+2) — tiny payload, direct tag poll
        const u32* xsl = x1r + (size_t)((t + 1) & 15) * PSLOT;
        u32x2 xq[4];
        for (;;) {
          #pragma unroll
          for (int j = 0; j < 4; ++j) {
            const int b = g * 16 + lhi * 4 + j;
            xq[j] = ld_sc1_x2(xsl + (((size_t)b * 512 + n) << 1));
          }
          vm0_fence();
          u32 bad = 0;
          #pragma unroll
          for (int j = 0; j < 4; ++j) bad |= xq[j].y ^ (u32)(t + 2);
          if (!bad) break;
        }
        #pragma unroll
        for (int j = 0; j < 4; ++j) xvb[j] = xq[j].x;
      }
      __syncthreads();
    }
  }
}

// ---------------------------------------------------------------------------
// out = h1 @ Why^T + by. 64-row M-blocks (Why re-read /4 vs 16-row tiles).
// ---------------------------------------------------------------------------
__global__ void k_gemm_out(const u16* __restrict__ A, const float* __restrict__ Bw,
                           const float* __restrict__ bias, float* __restrict__ outp) {
  const int tid  = threadIdx.x;
  const int wave = tid >> 6, lane = tid & 63;
  const int l15 = lane & 15, lhi = lane >> 4;
  const int M0  = blockIdx.x * 64;
  const int ncb = wave * 64;

  #pragma unroll
  for (int nt = 0; nt < 4; ++nt) {
    const int nn = ncb + nt * 16 + l15;
    const float* wr = Bw + (size_t)nn * H_ + lhi * 8;
    bf16x8 w[16];
    #pragma unroll
    for (int ks = 0; ks < 16; ++ks) {
      const float* src = wr + ks * 32;
      bf16x8 ww;
      #pragma unroll
      for (int j = 0; j < 8; ++j) ww[j] = (short)f2bf(src[j]);
      w[ks] = ww;
    }
    const float bs = bias[nn];
    for (int mi = 0; mi < 4; ++mi) {
      const int m0 = M0 + mi * 16;
      const u16* arow = A + ((size_t)(m0 + l15)) * H_ + lhi * 8;
      f32x4 acc = {0.f, 0.f, 0.f, 0.f};
      #pragma unroll
      for (int ks = 0; ks < 16; ++ks) {
        bf16x8 a = *(const bf16x8*)(arow + ks * 32);
        acc = __builtin_amdgcn_mfma_f32_16x16x32_bf16(a, w[ks], acc, 0, 0, 0);
      }
      #pragma unroll
      for (int j = 0; j < 4; ++j)
        outp[(size_t)(m0 + lhi * 4 + j) * O_ + nn] = acc[j] + bs;
    }
  }
}

// ---------------------------------------------------------------------------
extern "C" void kernel_launch(void* const* d_in, const int* in_sizes, int n_in,
                              void* d_out, int out_size, void* d_ws, size_t ws_size,
                              hipStream_t stream) {
  const int*   ids = (const int*)d_in[0];
  const float* emb = (const float*)d_in[1];
  const float* Wxh = (const float*)d_in[2];
  const float* Whh = (const float*)d_in[3];
  const float* bh  = (const float*)d_in[4];
  const float* Why = (const float*)d_in[5];
  const float* by  = (const float*)d_in[6];
  float* out = (float*)d_out;

  char* ws = (char*)d_ws;
  size_t off = 0;
  float* EW0  = (float*)(ws + off); off += (size_t)V_ * H_ * 4;        // 256 KB
  u32* h0r    = (u32*)(ws + off);   off += (size_t)16 * PSLOT * 4;     // 4 MB
  u32* x1r    = (u32*)(ws + off);   off += (size_t)16 * PSLOT * 4;     // 4 MB
  u32* h1r    = (u32*)(ws + off);   off += (size_t)4 * PSLOT * 4;      // 1 MB
  u32* fa     = (u32*)(ws + off);   off += 4096;                       // flag arena
  u16* h1full = (u16*)(ws + off);   off += (size_t)B_ * S_ * H_ * 2;   // 67 MB

  // rings + flags must be zero each call: stale tags from a previous replay
  // are EXACTLY the values the next run polls for (tags are t+1 in [1,1024]).
  const size_t zlen = (size_t)(16 + 16 + 4) * PSLOT * 4 + 4096;
  hipMemsetAsync(h0r, 0, zlen, stream);

  k_embed<<<dim3(V_), dim3(256), 0, stream>>>(emb, Wxh, bh, EW0);

  k_pipe<<<dim3(48), dim3(512), 0, stream>>>(Whh, Wxh, ids, EW0, bh,
                                             h0r, x1r, h1r, h1full, fa);

  k_gemm_out<<<dim3((B_ * S_) / 64), dim3(256), 0, stream>>>(h1full, Why, by, out);
}

// Round 10
// 3598.123 us; speedup vs baseline: 1.1882x; 1.1882x over previous
//
#include <hip/hip_runtime.h>
#include <stdint.h>

// CipherRNN: B=64, S=1024, V=128, E=512, H=512, L=2, O=256
#define B_ 64
#define S_ 1024
#define V_ 128
#define E_ 512
#define H_ 512
#define O_ 256
#define SLOTU 32768              // u32 per compact ring slot (64 rows x 512 cols)

typedef __attribute__((ext_vector_type(8))) short bf16x8;
typedef __attribute__((ext_vector_type(4))) float f32x4;
typedef __attribute__((ext_vector_type(4))) unsigned int u32x4;
typedef __attribute__((ext_vector_type(2))) unsigned int u32x2;
typedef unsigned short u16;
typedef unsigned int u32;

__device__ __forceinline__ u16 f2bf(float f) {
  unsigned u = __builtin_bit_cast(unsigned, f);
  u = u + 0x7FFFu + ((u >> 16) & 1u);   // RNE
  return (u16)(u >> 16);
}
__device__ __forceinline__ float bf2f(u16 h) {
  unsigned u = ((unsigned)h) << 16;
  return __builtin_bit_cast(float, u);
}
// fast tanh via exp2 (~1e-7 rel err; numerically proven rounds 4/7/8/9)
__device__ __forceinline__ float fast_tanh(float x) {
  float a = __builtin_amdgcn_exp2f(x * 2.8853900817779268f);
  return 1.0f - 2.0f * __builtin_amdgcn_rcpf(a + 1.0f);
}
__device__ __forceinline__ u32 pk_hi(u32 a, u32 b) { return (a & 0xffffu) | (b << 16); }
__device__ __forceinline__ u32 pk_lo(u32 a, u32 b) { return (a >> 16) | (b & 0xffff0000u); }

// ---- device-coherent (bypass L1+L2, zero cache-maintenance) ops — proven r3..r9
__device__ __forceinline__ u32x4 ld_sc1_x4(const u32* p) {
  u32x4 v;
  asm volatile("global_load_dwordx4 %0, %1, off sc0 sc1" : "=v"(v) : "v"(p));
  return v;
}
__device__ __forceinline__ u32 ld_sc1_u32(const u32* p) {
  u32 v;
  asm volatile("global_load_dword %0, %1, off sc0 sc1" : "=v"(v) : "v"(p));
  return v;
}
__device__ __forceinline__ void st_sc1_u32(u32* p, u32 v) {
  asm volatile("global_store_dword %0, %1, off sc0 sc1" :: "v"(p), "v"(v) : "memory");
}
__device__ __forceinline__ void st_short_nt(u16* p, u32 v) {
  asm volatile("global_store_short %0, %1, off nt" :: "v"(p), "v"(v) : "memory");
}
__device__ __forceinline__ void vm0_fence() {
  asm volatile("s_waitcnt vmcnt(0)" ::: "memory");
  __builtin_amdgcn_sched_barrier(0);
}
// rare tid0 backpressure gate (16B flag-line poll)
__device__ __forceinline__ void poll4(const u32* p, u32 tgt) {
  for (;;) {
    u32x4 v;
    asm volatile("global_load_dwordx4 %0, %1, off sc0 sc1\n\ts_waitcnt vmcnt(0)"
                 : "=v"(v) : "v"(p) : "memory");
    if (v.x >= tgt && v.y >= tgt && v.z >= tgt && v.w >= tgt) return;
    __builtin_amdgcn_s_sleep(1);
  }
}

// ---------------------------------------------------------------------------
// EW0[v][n] = sum_e emb[v][e]*Wxh0[n][e] + bh0[n]   (f32 exact, V=128)
// ---------------------------------------------------------------------------
__global__ void k_embed(const float* __restrict__ emb, const float* __restrict__ Wxh0,
                        const float* __restrict__ bh0, float* __restrict__ EW0) {
  __shared__ float es[E_];
  const int v = blockIdx.x;
  for (int e = threadIdx.x; e < E_; e += blockDim.x) es[e] = emb[v * E_ + e];
  __syncthreads();
  for (int h = threadIdx.x; h < H_; h += blockDim.x) {
    const float* wr = Wxh0 + (size_t)h * E_;
    float acc = bh0[h];
    #pragma unroll 4
    for (int e = 0; e < E_; e += 4)
      acc += es[e] * wr[e] + es[e+1] * wr[e+1] + es[e+2] * wr[e+2] + es[e+3] * wr[e+3];
    EW0[(size_t)v * H_ + h] = acc;
  }
}

// ---------------------------------------------------------------------------
// Persistent 3-stage pipeline, PHASE-BIT protocol: compact u32 ring words carry
// an epoch bit (h: bit16 = lo-bf16 LSB; x1: bit0 = f32 mantissa LSB). Phase
// flips each ring wrap; memset-0 and stale epochs always mismatch. Producers
// never drain, post no flags; consumers retry-read their compact slices.
// 48 blocks = 3 roles x 4 groups (16 batch rows) x 4 col-blocks (128 cols).
// ---------------------------------------------------------------------------
__global__ __launch_bounds__(512, 2) void k_pipe(
    const float* __restrict__ Whh, const float* __restrict__ Wxh,
    const int* __restrict__ ids, const float* __restrict__ EW0,
    const float* __restrict__ bh,
    u32* __restrict__ h0r,        // [16][64*512] packed {hb | lb<<16}, bit16=phase
    u32* __restrict__ x1r,        // [16][64*512] f32 bits, bit0=phase
    u32* __restrict__ h1r,        // [4][64*512] packed, bit16=phase
    u16* __restrict__ h1full,     // [B*S][512] bf16
    u32* __restrict__ fa)         // backpressure arena (zeroed each call)
{
  __shared__ u32 lds_hi_w[2 * 4096];   // 2 bufs x 16 rows x 512 u16 cols (hi)
  __shared__ u32 lds_lo_w[2 * 4096];   // (lo)

  const int tid  = threadIdx.x;
  const int wave = tid >> 6, lane = tid & 63;
  const int l15 = lane & 15, lhi = lane >> 4;
  const int bid = blockIdx.x;
  const int role = bid >> 4, sub = bid & 15;
  const int g = sub >> 2, cb = sub & 3;
  const int n = cb * 128 + wave * 16 + l15;   // this lane's output column

  u32* x1prog = fa;        // [4g][4cb] role1 progress (h0/x1 ring backpressure)
  u32* r2prog = fa + 16;   // [4g][4cb] role2 progress

  // ---- resident weights (hi/lo bf16 B-fragments), plain cached loads ----
  const float* Wsel = (role == 0) ? Whh
                    : (role == 1) ? (Wxh + (size_t)H_ * H_)
                                  : (Whh + (size_t)H_ * H_);
  bf16x8 whi[16], wlo[16];
  {
    const float* wr = Wsel + (size_t)n * H_ + lhi * 8;
    #pragma unroll
    for (int ks = 0; ks < 16; ++ks) {
      const float* src = wr + ks * 32;
      bf16x8 h, l;
      #pragma unroll
      for (int j = 0; j < 8; ++j) {
        const float v = src[j];
        const u16 hb = f2bf(v);
        h[j] = (short)hb;
        l[j] = (short)f2bf(v - bf2f(hb));
      }
      whi[ks] = h; wlo[ks] = l;
    }
  }

  // A-frag swizzled LDS byte offsets: row=l15, granule = ks*4+lhi
  int aoff[16];
  {
    const int sw = l15 & 7;
    #pragma unroll
    for (int ks = 0; ks < 16; ++ks)
      aoff[ks] = l15 * 1024 + (((ks * 4 + lhi) ^ sw) << 4);
  }

  // staging geometry: 16 rows x 32 4-col chunks per 128-col slice
  const int sr = tid >> 5, sm = tid & 31;
  const int rowbase = (g * 16 + sr) * 512;     // u32 row base within a slot

  auto wr_lds = [&](int buf, int cs, u32x4 q) {
    const int byte = buf * 16384 + sr * 1024 + (sm & 1) * 8 +
                     ((((cs << 4) + (sm >> 1)) ^ (sr & 7)) << 4);
    u32x2 hi = { pk_hi(q.x, q.y), pk_hi(q.z, q.w) };
    u32x2 lo = { pk_lo(q.x, q.y), pk_lo(q.z, q.w) };
    *(u32x2*)((char*)lds_hi_w + byte) = hi;
    *(u32x2*)((char*)lds_lo_w + byte) = lo;
  };

  // retry-stage the 3 sibling 16x128 slices (48B/thread/try), phase-checked
  auto pollstage3 = [&](const u32* slot, u32 ph16, int buf) {
    const int c0 = (cb + 1) & 3, c1 = (cb + 2) & 3, c2 = (cb + 3) & 3;
    const u32* p0 = slot + rowbase + c0 * 128 + sm * 4;
    const u32* p1 = slot + rowbase + c1 * 128 + sm * 4;
    const u32* p2 = slot + rowbase + c2 * 128 + sm * 4;
    u32x4 a, b, d;
    for (;;) {
      a = ld_sc1_x4(p0); b = ld_sc1_x4(p1); d = ld_sc1_x4(p2);
      vm0_fence();
      u32 bad = ((a.x ^ ph16) | (a.y ^ ph16) | (a.z ^ ph16) | (a.w ^ ph16)
               | (b.x ^ ph16) | (b.y ^ ph16) | (b.z ^ ph16) | (b.w ^ ph16)
               | (d.x ^ ph16) | (d.y ^ ph16) | (d.z ^ ph16) | (d.w ^ ph16)) & 0x10000u;
      if (!bad) break;
    }
    wr_lds(buf, c0, a); wr_lds(buf, c1, b); wr_lds(buf, c2, d);
  };

  // retry-stage all 4 slices (role 1; 64B/thread/try)
  auto pollstage4 = [&](const u32* slot, u32 ph16, int buf) {
    const u32* p = slot + rowbase + sm * 4;
    u32x4 q0, q1, q2, q3;
    for (;;) {
      q0 = ld_sc1_x4(p);       q1 = ld_sc1_x4(p + 128);
      q2 = ld_sc1_x4(p + 256); q3 = ld_sc1_x4(p + 384);
      vm0_fence();
      u32 bad = ((q0.x ^ ph16) | (q0.y ^ ph16) | (q0.z ^ ph16) | (q0.w ^ ph16)
               | (q1.x ^ ph16) | (q1.y ^ ph16) | (q1.z ^ ph16) | (q1.w ^ ph16)
               | (q2.x ^ ph16) | (q2.y ^ ph16) | (q2.z ^ ph16) | (q2.w ^ ph16)
               | (q3.x ^ ph16) | (q3.y ^ ph16) | (q3.z ^ ph16) | (q3.w ^ ph16)) & 0x10000u;
      if (!bad) break;
    }
    wr_lds(buf, 0, q0); wr_lds(buf, 1, q1); wr_lds(buf, 2, q2); wr_lds(buf, 3, q3);
  };

  // emulated-fp32 matmul from LDS tile (3 independent MFMA chains)
  auto mm3 = [&](int buf, f32x4& out) {
    const char* bh_ = (const char*)lds_hi_w + buf * 16384;
    const char* bl_ = (const char*)lds_lo_w + buf * 16384;
    f32x4 c0 = {0.f,0.f,0.f,0.f}, c1 = c0, c2 = c0;
    #pragma unroll
    for (int ks = 0; ks < 16; ++ks) {
      bf16x8 ah = *(const bf16x8*)(bh_ + aoff[ks]);
      bf16x8 al = *(const bf16x8*)(bl_ + aoff[ks]);
      c0 = __builtin_amdgcn_mfma_f32_16x16x32_bf16(ah, whi[ks], c0, 0, 0, 0);
      c1 = __builtin_amdgcn_mfma_f32_16x16x32_bf16(al, whi[ks], c1, 0, 0, 0);
      c2 = __builtin_amdgcn_mfma_f32_16x16x32_bf16(ah, wlo[ks], c2, 0, 0, 0);
    }
    out = c0 + c1 + c2;
  };

  // epilogue self-write: own 4 outputs (col n, rows lhi*4+j) into LDS buf
  auto self_write = [&](int buf, const u16* hbv, const u16* lbv) {
    char* bh_ = (char*)lds_hi_w + buf * 16384;
    char* bl_ = (char*)lds_lo_w + buf * 16384;
    const int gcol = n >> 3, coff = (n & 7) * 2;
    #pragma unroll
    for (int j = 0; j < 4; ++j) {
      const int r = lhi * 4 + j;
      const int byte = r * 1024 + ((gcol ^ (r & 7)) << 4) + coff;
      *(u16*)(bh_ + byte) = hbv[j];
      *(u16*)(bl_ + byte) = lbv[j];
    }
  };

  if (role == 0) {                     // ======== layer-0 recurrence ========
    int cur = 0;
    for (int t = 0; t < S_; ++t) {
      if ((t & 7) == 0 && t >= 16) {   // gate BEFORE this step's ring write
        if (tid == 0) poll4(&x1prog[g * 4], (u32)(t - 8));
        __syncthreads();
      }
      float ew[4];
      #pragma unroll
      for (int j = 0; j < 4; ++j) {
        const int b = g * 16 + lhi * 4 + j;
        ew[j] = EW0[(size_t)ids[b * S_ + t] * H_ + n];
      }
      f32x4 acc = {0.f,0.f,0.f,0.f};
      if (t > 0) mm3(cur, acc);        // buf cur holds h0[t-1]
      const u32 ph = (((u32)t >> 4) & 1u) ^ 1u;   // epoch phase for slot t&15
      u32* wsl = h0r + (size_t)(t & 15) * SLOTU;
      u16 hbv[4], lbv[4];
      #pragma unroll
      for (int j = 0; j < 4; ++j) {
        const int b = g * 16 + lhi * 4 + j;
        const float h = fast_tanh(acc[j] + ew[j]);
        hbv[j] = f2bf(h);
        lbv[j] = (u16)((f2bf(h - bf2f(hbv[j])) & 0xFFFEu) | ph);   // phase in LSB
        st_sc1_u32(wsl + (size_t)b * 512 + n, (u32)hbv[j] | ((u32)lbv[j] << 16));
      }
      self_write(cur ^ 1, hbv, lbv);
      if (t + 1 < S_) pollstage3(wsl, ph << 16, cur ^ 1);
      __syncthreads();
      cur ^= 1;
    }
  } else if (role == 1) {              // ======== x1 = h0 @ Wxh1^T + bh1 ========
    const float bias = bh[H_ + n];
    int cur = 0;
    for (int t = 0; t < S_; ++t) {
      if ((t & 7) == 0 && t >= 16) {   // gate BEFORE this step's x1 ring write
        if (tid == 0) poll4(&r2prog[g * 4], (u32)(t - 8));
        __syncthreads();
      }
      const u32 ph = (((u32)t >> 4) & 1u) ^ 1u;
      pollstage4(h0r + (size_t)(t & 15) * SLOTU, ph << 16, cur);
      __syncthreads();
      f32x4 acc;
      mm3(cur, acc);
      u32* xsl = x1r + (size_t)(t & 15) * SLOTU;
      #pragma unroll
      for (int j = 0; j < 4; ++j) {
        const int b = g * 16 + lhi * 4 + j;
        const u32 w = (__builtin_bit_cast(u32, acc[j] + bias) & ~1u) | ph;
        st_sc1_u32(xsl + (size_t)b * 512 + n, w);
      }
      if ((t & 7) == 7 && tid == 0)    // h0(t) consumed; release ring slots
        st_sc1_u32(&x1prog[g * 4 + cb], (u32)(t + 1));
      cur ^= 1;
    }
  } else {                             // ======== layer-1 recurrence ========
    u32 xvb[4];
    {                                   // pre-loop: phase-poll x1(0) own 16B
      u32 x0, x1v, x2, x3;
      for (;;) {
        const int b = g * 16 + lhi * 4;
        x0 = ld_sc1_u32(x1r + (size_t)b * 512 + n);
        x1v = ld_sc1_u32(x1r + (size_t)(b + 1) * 512 + n);
        x2 = ld_sc1_u32(x1r + (size_t)(b + 2) * 512 + n);
        x3 = ld_sc1_u32(x1r + (size_t)(b + 3) * 512 + n);
        vm0_fence();
        if (((x0 & x1v & x2 & x3) & 1u) == 1u) break;   // phase 1 for t=0
      }
      xvb[0] = x0; xvb[1] = x1v; xvb[2] = x2; xvb[3] = x3;
    }
    int cur = 0;
    for (int t = 0; t < S_; ++t) {
      f32x4 acc = {0.f,0.f,0.f,0.f};
      if (t > 0) mm3(cur, acc);        // buf cur holds h1[t-1]
      const u32 ph1 = (((u32)t >> 2) & 1u) ^ 1u;  // h1 ring (depth 4) phase
      u32* wsl = h1r + (size_t)(t & 3) * SLOTU;
      u16 hbv[4], lbv[4];
      #pragma unroll
      for (int j = 0; j < 4; ++j) {
        const int b = g * 16 + lhi * 4 + j;
        const float h = fast_tanh(acc[j] + __builtin_bit_cast(float, xvb[j]));
        hbv[j] = f2bf(h);
        lbv[j] = (u16)((f2bf(h - bf2f(hbv[j])) & 0xFFFEu) | ph1);
        st_sc1_u32(wsl + (size_t)b * 512 + n, (u32)hbv[j] | ((u32)lbv[j] << 16));
        st_short_nt(h1full + ((size_t)b * S_ + t) * H_ + n, (u32)hbv[j]);
      }
      self_write(cur ^ 1, hbv, lbv);
      if ((t & 7) == 7 && tid == 0)    // x1 consumed up to t+1; release slots
        st_sc1_u32(&r2prog[g * 4 + cb], (u32)(t + 1));
      if (t + 1 < S_) {
        // combined retry: h1(t) sibling slices + own x1(t+1) 16B
        const u32 ph16 = ph1 << 16;
        const u32 phx = ((((u32)(t + 1)) >> 4) & 1u) ^ 1u;
        const int c0 = (cb + 1) & 3, c1 = (cb + 2) & 3, c2 = (cb + 3) & 3;
        const u32* p0 = wsl + rowbase + c0 * 128 + sm * 4;
        const u32* p1 = wsl + rowbase + c1 * 128 + sm * 4;
        const u32* p2 = wsl + rowbase + c2 * 128 + sm * 4;
        const u32* xsl = x1r + (size_t)((t + 1) & 15) * SLOTU;
        const int b0 = g * 16 + lhi * 4;
        u32x4 a, b, d;
        u32 x0, x1v, x2, x3;
        for (;;) {
          a = ld_sc1_x4(p0); b = ld_sc1_x4(p1); d = ld_sc1_x4(p2);
          x0 = ld_sc1_u32(xsl + (size_t)b0 * 512 + n);
          x1v = ld_sc1_u32(xsl + (size_t)(b0 + 1) * 512 + n);
          x2 = ld_sc1_u32(xsl + (size_t)(b0 + 2) * 512 + n);
          x3 = ld_sc1_u32(xsl + (size_t)(b0 + 3) * 512 + n);
          vm0_fence();
          u32 bad = ((a.x ^ ph16) | (a.y ^ ph16) | (a.z ^ ph16) | (a.w ^ ph16)
                   | (b.x ^ ph16) | (b.y ^ ph16) | (b.z ^ ph16) | (b.w ^ ph16)
                   | (d.x ^ ph16) | (d.y ^ ph16) | (d.z ^ ph16) | (d.w ^ ph16)) & 0x10000u;
          bad |= ((x0 ^ phx) | (x1v ^ phx) | (x2 ^ phx) | (x3 ^ phx)) & 1u;
          if (!bad) break;
        }
        wr_lds(cur ^ 1, c0, a); wr_lds(cur ^ 1, c1, b); wr_lds(cur ^ 1, c2, d);
        xvb[0] = x0; xvb[1] = x1v; xvb[2] = x2; xvb[3] = x3;
      }
      __syncthreads();
      cur ^= 1;
    }
  }
}

// ---------------------------------------------------------------------------
// out = h1 @ Why^T + by. 64-row M-blocks (Why re-read /4 vs 16-row tiles).
// ---------------------------------------------------------------------------
__global__ void k_gemm_out(const u16* __restrict__ A, const float* __restrict__ Bw,
                           const float* __restrict__ bias, float* __restrict__ outp) {
  const int tid  = threadIdx.x;
  const int wave = tid >> 6, lane = tid & 63;
  const int l15 = lane & 15, lhi = lane >> 4;
  const int M0  = blockIdx.x * 64;
  const int ncb = wave * 64;

  #pragma unroll
  for (int nt = 0; nt < 4; ++nt) {
    const int nn = ncb + nt * 16 + l15;
    const float* wr = Bw + (size_t)nn * H_ + lhi * 8;
    bf16x8 w[16];
    #pragma unroll
    for (int ks = 0; ks < 16; ++ks) {
      const float* src = wr + ks * 32;
      bf16x8 ww;
      #pragma unroll
      for (int j = 0; j < 8; ++j) ww[j] = (short)f2bf(src[j]);
      w[ks] = ww;
    }
    const float bs = bias[nn];
    for (int mi = 0; mi < 4; ++mi) {
      const int m0 = M0 + mi * 16;
      const u16* arow = A + ((size_t)(m0 + l15)) * H_ + lhi * 8;
      f32x4 acc = {0.f, 0.f, 0.f, 0.f};
      #pragma unroll
      for (int ks = 0; ks < 16; ++ks) {
        bf16x8 a = *(const bf16x8*)(arow + ks * 32);
        acc = __builtin_amdgcn_mfma_f32_16x16x32_bf16(a, w[ks], acc, 0, 0, 0);
      }
      #pragma unroll
      for (int j = 0; j < 4; ++j)
        outp[(size_t)(m0 + lhi * 4 + j) * O_ + nn] = acc[j] + bs;
    }
  }
}

// ---------------------------------------------------------------------------
extern "C" void kernel_launch(void* const* d_in, const int* in_sizes, int n_in,
                              void* d_out, int out_size, void* d_ws, size_t ws_size,
                              hipStream_t stream) {
  const int*   ids = (const int*)d_in[0];
  const float* emb = (const float*)d_in[1];
  const float* Wxh = (const float*)d_in[2];
  const float* Whh = (const float*)d_in[3];
  const float* bh  = (const float*)d_in[4];
  const float* Why = (const float*)d_in[5];
  const float* by  = (const float*)d_in[6];
  float* out = (float*)d_out;

  char* ws = (char*)d_ws;
  size_t off = 0;
  float* EW0  = (float*)(ws + off); off += (size_t)V_ * H_ * 4;        // 256 KB
  u32* h0r    = (u32*)(ws + off);   off += (size_t)16 * SLOTU * 4;     // 2 MB
  u32* x1r    = (u32*)(ws + off);   off += (size_t)16 * SLOTU * 4;     // 2 MB
  u32* h1r    = (u32*)(ws + off);   off += (size_t)4 * SLOTU * 4;      // 512 KB
  u32* fa     = (u32*)(ws + off);   off += 4096;                       // backpressure
  u16* h1full = (u16*)(ws + off);   off += (size_t)B_ * S_ * H_ * 2;   // 67 MB

  // rings + arena must be zero each call: phase protocol starts from epoch-1
  // expecting bit=1; memset-0 guarantees stale/initial words mismatch.
  const size_t zlen = (size_t)(16 + 16 + 4) * SLOTU * 4 + 4096;
  hipMemsetAsync(h0r, 0, zlen, stream);

  k_embed<<<dim3(V_), dim3(256), 0, stream>>>(emb, Wxh, bh, EW0);

  k_pipe<<<dim3(48), dim3(512), 0, stream>>>(Whh, Wxh, ids, EW0, bh,
                                             h0r, x1r, h1r, h1full, fa);

  k_gemm_out<<<dim3((B_ * S_) / 64), dim3(256), 0, stream>>>(h1full, Why, by, out);
}

// Round 13
// 3597.978 us; speedup vs baseline: 1.1882x; 1.0000x over previous
//
#include <hip/hip_runtime.h>
#include <stdint.h>

// CipherRNN: B=64, S=1024, V=128, E=512, H=512, L=2, O=256
#define B_ 64
#define S_ 1024
#define V_ 128
#define E_ 512
#define H_ 512
#define O_ 256
#define SLOTU 32768              // u32 per compact ring slot (64 rows x 512 cols)

typedef __attribute__((ext_vector_type(8))) short bf16x8;
typedef __attribute__((ext_vector_type(4))) float f32x4;
typedef __attribute__((ext_vector_type(4))) unsigned int u32x4;
typedef __attribute__((ext_vector_type(2))) unsigned int u32x2;
typedef unsigned short u16;
typedef unsigned int u32;

__device__ __forceinline__ u16 f2bf(float f) {
  unsigned u = __builtin_bit_cast(unsigned, f);
  u = u + 0x7FFFu + ((u >> 16) & 1u);   // RNE
  return (u16)(u >> 16);
}
__device__ __forceinline__ float bf2f(u16 h) {
  unsigned u = ((unsigned)h) << 16;
  return __builtin_bit_cast(float, u);
}
// fast tanh via exp2 (~1e-7 rel err; numerically proven rounds 4/7..10)
__device__ __forceinline__ float fast_tanh(float x) {
  float a = __builtin_amdgcn_exp2f(x * 2.8853900817779268f);
  return 1.0f - 2.0f * __builtin_amdgcn_rcpf(a + 1.0f);
}
__device__ __forceinline__ u32 pk_hi(u32 a, u32 b) { return (a & 0xffffu) | (b << 16); }
__device__ __forceinline__ u32 pk_lo(u32 a, u32 b) { return (a >> 16) | (b & 0xffff0000u); }

// ---- device-coherent (bypass L1+L2, zero cache-maintenance) ops — proven r3..r10
__device__ __forceinline__ u32x4 ld_sc1_x4(const u32* p) {
  u32x4 v;
  asm volatile("global_load_dwordx4 %0, %1, off sc0 sc1" : "=v"(v) : "v"(p));
  return v;
}
__device__ __forceinline__ u32 ld_sc1_u32(const u32* p) {
  u32 v;
  asm volatile("global_load_dword %0, %1, off sc0 sc1" : "=v"(v) : "v"(p));
  return v;
}
__device__ __forceinline__ void st_sc1_u32(u32* p, u32 v) {
  asm volatile("global_store_dword %0, %1, off sc0 sc1" :: "v"(p), "v"(v) : "memory");
}
__device__ __forceinline__ void st_short_nt(u16* p, u32 v) {
  asm volatile("global_store_short %0, %1, off nt" :: "v"(p), "v"(v) : "memory");
}
__device__ __forceinline__ void vm0_fence() {
  asm volatile("s_waitcnt vmcnt(0)" ::: "memory");
  __builtin_amdgcn_sched_barrier(0);
}
// rare tid0 backpressure gate (16B flag-line poll)
__device__ __forceinline__ void poll4(const u32* p, u32 tgt) {
  for (;;) {
    u32x4 v;
    asm volatile("global_load_dwordx4 %0, %1, off sc0 sc1\n\ts_waitcnt vmcnt(0)"
                 : "=v"(v) : "v"(p) : "memory");
    if (v.x >= tgt && v.y >= tgt && v.z >= tgt && v.w >= tgt) return;
    __builtin_amdgcn_s_sleep(1);
  }
}

// ---------------------------------------------------------------------------
// EW0[v][n] = sum_e emb[v][e]*Wxh0[n][e] + bh0[n]   (f32 exact, V=128)
// ---------------------------------------------------------------------------
__global__ void k_embed(const float* __restrict__ emb, const float* __restrict__ Wxh0,
                        const float* __restrict__ bh0, float* __restrict__ EW0) {
  __shared__ float es[E_];
  const int v = blockIdx.x;
  for (int e = threadIdx.x; e < E_; e += blockDim.x) es[e] = emb[v * E_ + e];
  __syncthreads();
  for (int h = threadIdx.x; h < H_; h += blockDim.x) {
    const float* wr = Wxh0 + (size_t)h * E_;
    float acc = bh0[h];
    #pragma unroll 4
    for (int e = 0; e < E_; e += 4)
      acc += es[e] * wr[e] + es[e+1] * wr[e+1] + es[e+2] * wr[e+2] + es[e+3] * wr[e+3];
    EW0[(size_t)v * H_ + h] = acc;
  }
}

// ---------------------------------------------------------------------------
// Persistent 3-stage pipeline, PHASE-BIT protocol (r10, proven 3380us) plus
// L3 warm-prefetch with DESTINATION-LIVENESS FIX: warm-load results are kept
// in named registers and pinned live (asm keep-alive) past the vmcnt(0) that
// drains them — an in-flight global_load writes its dest VGPR at completion,
// so discarding the result lets the allocator reuse the register and the
// late write clobbers it (the r11/r12 crash).
// 48 blocks = 3 roles x 4 groups (16 batch rows) x 4 col-blocks (128 cols).
// ---------------------------------------------------------------------------
__global__ __launch_bounds__(512, 2) void k_pipe(
    const float* __restrict__ Whh, const float* __restrict__ Wxh,
    const int* __restrict__ ids, const float* __restrict__ EW0,
    const float* __restrict__ bh,
    u32* __restrict__ h0r,        // [16][64*512] packed {hb | lb<<16}, bit16=phase
    u32* __restrict__ x1r,        // [16][64*512] f32 bits, bit0=phase
    u32* __restrict__ h1r,        // [4][64*512] packed, bit16=phase
    u16* __restrict__ h1full,     // [B*S][512] bf16
    u32* __restrict__ fa)         // backpressure arena (zeroed each call)
{
  __shared__ u32 lds_hi_w[2 * 4096];   // 2 bufs x 16 rows x 512 u16 cols (hi)
  __shared__ u32 lds_lo_w[2 * 4096];   // (lo)

  const int tid  = threadIdx.x;
  const int wave = tid >> 6, lane = tid & 63;
  const int l15 = lane & 15, lhi = lane >> 4;
  const int bid = blockIdx.x;
  const int role = bid >> 4, sub = bid & 15;
  const int g = sub >> 2, cb = sub & 3;
  const int n = cb * 128 + wave * 16 + l15;   // this lane's output column

  u32* x1prog = fa;        // [4g][4cb] role1 progress (h0 ring backpressure)
  u32* r2prog = fa + 16;   // [4g][4cb] role2 progress (x1 ring backpressure)

  // ---- resident weights (hi/lo bf16 B-fragments), plain cached loads ----
  const float* Wsel = (role == 0) ? Whh
                    : (role == 1) ? (Wxh + (size_t)H_ * H_)
                                  : (Whh + (size_t)H_ * H_);
  bf16x8 whi[16], wlo[16];
  {
    const float* wr = Wsel + (size_t)n * H_ + lhi * 8;
    #pragma unroll
    for (int ks = 0; ks < 16; ++ks) {
      const float* src = wr + ks * 32;
      bf16x8 h, l;
      #pragma unroll
      for (int j = 0; j < 8; ++j) {
        const float v = src[j];
        const u16 hb = f2bf(v);
        h[j] = (short)hb;
        l[j] = (short)f2bf(v - bf2f(hb));
      }
      whi[ks] = h; wlo[ks] = l;
    }
  }

  // A-frag swizzled LDS byte offsets: row=l15, granule = ks*4+lhi
  int aoff[16];
  {
    const int sw = l15 & 7;
    #pragma unroll
    for (int ks = 0; ks < 16; ++ks)
      aoff[ks] = l15 * 1024 + (((ks * 4 + lhi) ^ sw) << 4);
  }

  // staging geometry: 16 rows x 32 4-col chunks per 128-col slice
  const int sr = tid >> 5, sm = tid & 31;
  const int rowbase = (g * 16 + sr) * 512;     // u32 row base within a slot

  auto wr_lds = [&](int buf, int cs, u32x4 q) {
    const int byte = buf * 16384 + sr * 1024 + (sm & 1) * 8 +
                     ((((cs << 4) + (sm >> 1)) ^ (sr & 7)) << 4);
    u32x2 hi = { pk_hi(q.x, q.y), pk_hi(q.z, q.w) };
    u32x2 lo = { pk_lo(q.x, q.y), pk_lo(q.z, q.w) };
    *(u32x2*)((char*)lds_hi_w + byte) = hi;
    *(u32x2*)((char*)lds_lo_w + byte) = lo;
  };

  // retry-stage 3 sibling slices; warm next slot's lines (results kept LIVE)
  auto pollstage3 = [&](const u32* slot, u32 ph16, int buf, const u32* warm) {
    const int c0 = (cb + 1) & 3, c1 = (cb + 2) & 3, c2 = (cb + 3) & 3;
    const u32* p0 = slot + rowbase + c0 * 128 + sm * 4;
    const u32* p1 = slot + rowbase + c1 * 128 + sm * 4;
    const u32* p2 = slot + rowbase + c2 * 128 + sm * 4;
    u32x4 w0 = ld_sc1_x4(warm + rowbase + c0 * 128 + sm * 4);   // L3 pre-allocation
    u32x4 w1 = ld_sc1_x4(warm + rowbase + c1 * 128 + sm * 4);
    u32x4 w2 = ld_sc1_x4(warm + rowbase + c2 * 128 + sm * 4);
    u32x4 a, b, d;
    for (;;) {
      a = ld_sc1_x4(p0); b = ld_sc1_x4(p1); d = ld_sc1_x4(p2);
      vm0_fence();
      asm volatile("" :: "v"(w0), "v"(w1), "v"(w2));   // dests live past drain
      u32 bad = ((a.x ^ ph16) | (a.y ^ ph16) | (a.z ^ ph16) | (a.w ^ ph16)
               | (b.x ^ ph16) | (b.y ^ ph16) | (b.z ^ ph16) | (b.w ^ ph16)
               | (d.x ^ ph16) | (d.y ^ ph16) | (d.z ^ ph16) | (d.w ^ ph16)) & 0x10000u;
      if (!bad) break;
    }
    wr_lds(buf, c0, a); wr_lds(buf, c1, b); wr_lds(buf, c2, d);
  };

  // retry-stage all 4 slices (role 1); warm next slot (results kept LIVE)
  auto pollstage4 = [&](const u32* slot, u32 ph16, int buf, const u32* warm) {
    const u32* p = slot + rowbase + sm * 4;
    const u32* w = warm + rowbase + sm * 4;
    u32x4 w0 = ld_sc1_x4(w);       u32x4 w1 = ld_sc1_x4(w + 128);
    u32x4 w2 = ld_sc1_x4(w + 256); u32x4 w3 = ld_sc1_x4(w + 384);
    u32x4 q0, q1, q2, q3;
    for (;;) {
      q0 = ld_sc1_x4(p);       q1 = ld_sc1_x4(p + 128);
      q2 = ld_sc1_x4(p + 256); q3 = ld_sc1_x4(p + 384);
      vm0_fence();
      asm volatile("" :: "v"(w0), "v"(w1), "v"(w2), "v"(w3));
      u32 bad = ((q0.x ^ ph16) | (q0.y ^ ph16) | (q0.z ^ ph16) | (q0.w ^ ph16)
               | (q1.x ^ ph16) | (q1.y ^ ph16) | (q1.z ^ ph16) | (q1.w ^ ph16)
               | (q2.x ^ ph16) | (q2.y ^ ph16) | (q2.z ^ ph16) | (q2.w ^ ph16)
               | (q3.x ^ ph16) | (q3.y ^ ph16) | (q3.z ^ ph16) | (q3.w ^ ph16)) & 0x10000u;
      if (!bad) break;
    }
    wr_lds(buf, 0, q0); wr_lds(buf, 1, q1); wr_lds(buf, 2, q2); wr_lds(buf, 3, q3);
  };

  // emulated-fp32 matmul from LDS tile (3 independent MFMA chains)
  auto mm3 = [&](int buf, f32x4& out) {
    const char* bh_ = (const char*)lds_hi_w + buf * 16384;
    const char* bl_ = (const char*)lds_lo_w + buf * 16384;
    f32x4 c0 = {0.f,0.f,0.f,0.f}, c1 = c0, c2 = c0;
    #pragma unroll
    for (int ks = 0; ks < 16; ++ks) {
      bf16x8 ah = *(const bf16x8*)(bh_ + aoff[ks]);
      bf16x8 al = *(const bf16x8*)(bl_ + aoff[ks]);
      c0 = __builtin_amdgcn_mfma_f32_16x16x32_bf16(ah, whi[ks], c0, 0, 0, 0);
      c1 = __builtin_amdgcn_mfma_f32_16x16x32_bf16(al, whi[ks], c1, 0, 0, 0);
      c2 = __builtin_amdgcn_mfma_f32_16x16x32_bf16(ah, wlo[ks], c2, 0, 0, 0);
    }
    out = c0 + c1 + c2;
  };

  // epilogue self-write: own 4 outputs (col n, rows lhi*4+j) into LDS buf
  auto self_write = [&](int buf, const u16* hbv, const u16* lbv) {
    char* bh_ = (char*)lds_hi_w + buf * 16384;
    char* bl_ = (char*)lds_lo_w + buf * 16384;
    const int gcol = n >> 3, coff = (n & 7) * 2;
    #pragma unroll
    for (int j = 0; j < 4; ++j) {
      const int r = lhi * 4 + j;
      const int byte = r * 1024 + ((gcol ^ (r & 7)) << 4) + coff;
      *(u16*)(bh_ + byte) = hbv[j];
      *(u16*)(bl_ + byte) = lbv[j];
    }
  };

  if (role == 0) {                     // ======== layer-0 recurrence ========
    int cur = 0;
    for (int t = 0; t < S_; ++t) {
      if ((t & 7) == 0 && t >= 16) {   // gate BEFORE this step's ring write
        if (tid == 0) poll4(&x1prog[g * 4], (u32)(t - 8));
        __syncthreads();
      }
      float ew[4];
      #pragma unroll
      for (int j = 0; j < 4; ++j) {
        const int b = g * 16 + lhi * 4 + j;
        ew[j] = EW0[(size_t)ids[b * S_ + t] * H_ + n];
      }
      f32x4 acc = {0.f,0.f,0.f,0.f};
      if (t > 0) mm3(cur, acc);        // buf cur holds h0[t-1]
      const u32 ph = (((u32)t >> 4) & 1u) ^ 1u;   // epoch phase for slot t&15
      u32* wsl = h0r + (size_t)(t & 15) * SLOTU;
      u16 hbv[4], lbv[4];
      #pragma unroll
      for (int j = 0; j < 4; ++j) {
        const int b = g * 16 + lhi * 4 + j;
        const float h = fast_tanh(acc[j] + ew[j]);
        hbv[j] = f2bf(h);
        lbv[j] = (u16)((f2bf(h - bf2f(hbv[j])) & 0xFFFEu) | ph);   // phase in LSB
        st_sc1_u32(wsl + (size_t)b * 512 + n, (u32)hbv[j] | ((u32)lbv[j] << 16));
      }
      self_write(cur ^ 1, hbv, lbv);
      if (t + 1 < S_)
        pollstage3(wsl, ph << 16, cur ^ 1, h0r + (size_t)((t + 1) & 15) * SLOTU);
      __syncthreads();
      cur ^= 1;
    }
  } else if (role == 1) {              // ======== x1 = h0 @ Wxh1^T + bh1 ========
    const float bias = bh[H_ + n];
    int cur = 0;
    for (int t = 0; t < S_; ++t) {
      if ((t & 7) == 0 && t >= 16) {   // gate BEFORE this step's x1 ring write
        if (tid == 0) poll4(&r2prog[g * 4], (u32)(t - 8));
        __syncthreads();
      }
      const u32 ph = (((u32)t >> 4) & 1u) ^ 1u;
      pollstage4(h0r + (size_t)(t & 15) * SLOTU, ph << 16, cur,
                 h0r + (size_t)((t + 1) & 15) * SLOTU);
      __syncthreads();
      f32x4 acc;
      mm3(cur, acc);
      u32* xsl = x1r + (size_t)(t & 15) * SLOTU;
      #pragma unroll
      for (int j = 0; j < 4; ++j) {
        const int b = g * 16 + lhi * 4 + j;
        const u32 w = (__builtin_bit_cast(u32, acc[j] + bias) & ~1u) | ph;
        st_sc1_u32(xsl + (size_t)b * 512 + n, w);
      }
      if ((t & 7) == 7 && tid == 0)    // h0(t) consumed; release ring slots
        st_sc1_u32(&x1prog[g * 4 + cb], (u32)(t + 1));
      cur ^= 1;
    }
  } else {                             // ======== layer-1 recurrence ========
    u32 xvb[4];
    {                                   // pre-loop: phase-poll x1(0) own 16B
      u32 x0, x1v, x2, x3;
      for (;;) {
        const int b = g * 16 + lhi * 4;
        x0 = ld_sc1_u32(x1r + (size_t)b * 512 + n);
        x1v = ld_sc1_u32(x1r + (size_t)(b + 1) * 512 + n);
        x2 = ld_sc1_u32(x1r + (size_t)(b + 2) * 512 + n);
        x3 = ld_sc1_u32(x1r + (size_t)(b + 3) * 512 + n);
        vm0_fence();
        if (((x0 & x1v & x2 & x3) & 1u) == 1u) break;   // phase 1 for t=0
      }
      xvb[0] = x0; xvb[1] = x1v; xvb[2] = x2; xvb[3] = x3;
    }
    int cur = 0;
    for (int t = 0; t < S_; ++t) {
      f32x4 acc = {0.f,0.f,0.f,0.f};
      if (t > 0) mm3(cur, acc);        // buf cur holds h1[t-1]
      const u32 ph1 = (((u32)t >> 2) & 1u) ^ 1u;  // h1 ring (depth 4) phase
      u32* wsl = h1r + (size_t)(t & 3) * SLOTU;
      u16 hbv[4], lbv[4];
      #pragma unroll
      for (int j = 0; j < 4; ++j) {
        const int b = g * 16 + lhi * 4 + j;
        const float h = fast_tanh(acc[j] + __builtin_bit_cast(float, xvb[j]));
        hbv[j] = f2bf(h);
        lbv[j] = (u16)((f2bf(h - bf2f(hbv[j])) & 0xFFFEu) | ph1);
        st_sc1_u32(wsl + (size_t)b * 512 + n, (u32)hbv[j] | ((u32)lbv[j] << 16));
        st_short_nt(h1full + ((size_t)b * S_ + t) * H_ + n, (u32)hbv[j]);
      }
      self_write(cur ^ 1, hbv, lbv);
      if ((t & 7) == 7 && tid == 0)    // x1 consumed up to t+1; release slots
        st_sc1_u32(&r2prog[g * 4 + cb], (u32)(t + 1));
      if (t + 1 < S_) {
        // combined retry: h1(t) sibling slices + own x1(t+1) 16B, with warming
        const u32 ph16 = ph1 << 16;
        const u32 phx = ((((u32)(t + 1)) >> 4) & 1u) ^ 1u;
        const int c0 = (cb + 1) & 3, c1 = (cb + 2) & 3, c2 = (cb + 3) & 3;
        const u32* p0 = wsl + rowbase + c0 * 128 + sm * 4;
        const u32* p1 = wsl + rowbase + c1 * 128 + sm * 4;
        const u32* p2 = wsl + rowbase + c2 * 128 + sm * 4;
        const u32* xsl = x1r + (size_t)((t + 1) & 15) * SLOTU;
        const int b0 = g * 16 + lhi * 4;
        // warm next h1 slot + next-next x1 lines — results kept LIVE below
        const u32* wh = h1r + (size_t)((t + 1) & 3) * SLOTU;
        u32x4 wh0 = ld_sc1_x4(wh + rowbase + c0 * 128 + sm * 4);
        u32x4 wh1 = ld_sc1_x4(wh + rowbase + c1 * 128 + sm * 4);
        u32x4 wh2 = ld_sc1_x4(wh + rowbase + c2 * 128 + sm * 4);
        const u32* wx = x1r + (size_t)((t + 2) & 15) * SLOTU;
        u32 wx0 = ld_sc1_u32(wx + (size_t)b0 * 512 + n);
        u32 wx1 = ld_sc1_u32(wx + (size_t)(b0 + 2) * 512 + n);
        u32x4 a, b, d;
        u32 x0, x1v, x2, x3;
        for (;;) {
          a = ld_sc1_x4(p0); b = ld_sc1_x4(p1); d = ld_sc1_x4(p2);
          x0 = ld_sc1_u32(xsl + (size_t)b0 * 512 + n);
          x1v = ld_sc1_u32(xsl + (size_t)(b0 + 1) * 512 + n);
          x2 = ld_sc1_u32(xsl + (size_t)(b0 + 2) * 512 + n);
          x3 = ld_sc1_u32(xsl + (size_t)(b0 + 3) * 512 + n);
          vm0_fence();
          asm volatile("" :: "v"(wh0), "v"(wh1), "v"(wh2), "v"(wx0), "v"(wx1));
          u32 bad = ((a.x ^ ph16) | (a.y ^ ph16) | (a.z ^ ph16) | (a.w ^ ph16)
                   | (b.x ^ ph16) | (b.y ^ ph16) | (b.z ^ ph16) | (b.w ^ ph16)
                   | (d.x ^ ph16) | (d.y ^ ph16) | (d.z ^ ph16) | (d.w ^ ph16)) & 0x10000u;
          bad |= ((x0 ^ phx) | (x1v ^ phx) | (x2 ^ phx) | (x3 ^ phx)) & 1u;
          if (!bad) break;
        }
        wr_lds(cur ^ 1, c0, a); wr_lds(cur ^ 1, c1, b); wr_lds(cur ^ 1, c2, d);
        xvb[0] = x0; xvb[1] = x1v; xvb[2] = x2; xvb[3] = x3;
      }
      __syncthreads();
      cur ^= 1;
    }
  }
}

// ---------------------------------------------------------------------------
// out = h1 @ Why^T + by. 64-row M-blocks (Why re-read /4 vs 16-row tiles).
// ---------------------------------------------------------------------------
__global__ void k_gemm_out(const u16* __restrict__ A, const float* __restrict__ Bw,
                           const float* __restrict__ bias, float* __restrict__ outp) {
  const int tid  = threadIdx.x;
  const int wave = tid >> 6, lane = tid & 63;
  const int l15 = lane & 15, lhi = lane >> 4;
  const int M0  = blockIdx.x * 64;
  const int ncb = wave * 64;

  #pragma unroll
  for (int nt = 0; nt < 4; ++nt) {
    const int nn = ncb + nt * 16 + l15;
    const float* wr = Bw + (size_t)nn * H_ + lhi * 8;
    bf16x8 w[16];
    #pragma unroll
    for (int ks = 0; ks < 16; ++ks) {
      const float* src = wr + ks * 32;
      bf16x8 ww;
      #pragma unroll
      for (int j = 0; j < 8; ++j) ww[j] = (short)f2bf(src[j]);
      w[ks] = ww;
    }
    const float bs = bias[nn];
    for (int mi = 0; mi < 4; ++mi) {
      const int m0 = M0 + mi * 16;
      const u16* arow = A + ((size_t)(m0 + l15)) * H_ + lhi * 8;
      f32x4 acc = {0.f, 0.f, 0.f, 0.f};
      #pragma unroll
      for (int ks = 0; ks < 16; ++ks) {
        bf16x8 a = *(const bf16x8*)(arow + ks * 32);
        acc = __builtin_amdgcn_mfma_f32_16x16x32_bf16(a, w[ks], acc, 0, 0, 0);
      }
      #pragma unroll
      for (int j = 0; j < 4; ++j)
        outp[(size_t)(m0 + lhi * 4 + j) * O_ + nn] = acc[j] + bs;
    }
  }
}

// ---------------------------------------------------------------------------
extern "C" void kernel_launch(void* const* d_in, const int* in_sizes, int n_in,
                              void* d_out, int out_size, void* d_ws, size_t ws_size,
                              hipStream_t stream) {
  const int*   ids = (const int*)d_in[0];
  const float* emb = (const float*)d_in[1];
  const float* Wxh = (const float*)d_in[2];
  const float* Whh = (const float*)d_in[3];
  const float* bh  = (const float*)d_in[4];
  const float* Why = (const float*)d_in[5];
  const float* by  = (const float*)d_in[6];
  float* out = (float*)d_out;

  char* ws = (char*)d_ws;
  size_t off = 0;
  float* EW0  = (float*)(ws + off); off += (size_t)V_ * H_ * 4;        // 256 KB
  u32* h0r    = (u32*)(ws + off);   off += (size_t)16 * SLOTU * 4;     // 2 MB
  u32* x1r    = (u32*)(ws + off);   off += (size_t)16 * SLOTU * 4;     // 2 MB
  u32* h1r    = (u32*)(ws + off);   off += (size_t)4 * SLOTU * 4;      // 512 KB
  u32* fa     = (u32*)(ws + off);   off += 4096;                       // backpressure
  u16* h1full = (u16*)(ws + off);   off += (size_t)B_ * S_ * H_ * 2;   // 67 MB

  // rings + arena must be zero each call: phase protocol starts from epoch-1
  // expecting bit=1; memset-0 guarantees stale/initial words mismatch.
  const size_t zlen = (size_t)(16 + 16 + 4) * SLOTU * 4 + 4096;
  hipMemsetAsync(h0r, 0, zlen, stream);

  k_embed<<<dim3(V_), dim3(256), 0, stream>>>(emb, Wxh, bh, EW0);

  k_pipe<<<dim3(48), dim3(512), 0, stream>>>(Whh, Wxh, ids, EW0, bh,
                                             h0r, x1r, h1r, h1full, fa);

  k_gemm_out<<<dim3((B_ * S_) / 64), dim3(256), 0, stream>>>(h1full, Why, by, out);
}